// Round 5
// baseline (240.823 us; speedup 1.0000x reference)
//
#include <hip/hip_runtime.h>
#include <hip/hip_bf16.h>

#define B_   2
#define S_   2048
#define H_   1024
#define NH_  16
#define DH_  64

typedef __attribute__((ext_vector_type(8))) __bf16 bf16x8;
typedef __attribute__((ext_vector_type(8))) unsigned short u16x8;
typedef __attribute__((ext_vector_type(4))) float f32x4;
typedef __attribute__((ext_vector_type(4))) short i16x4;

typedef const __attribute__((address_space(1))) unsigned int gu32_t;
typedef __attribute__((address_space(3))) unsigned int su32_t;

static __device__ inline unsigned short f2bf(float x) {
    union { float f; unsigned u; } v; v.f = x;
    unsigned r = v.u + 0x7fffu + ((v.u >> 16) & 1u);
    return (unsigned short)(r >> 16);
}

// fast round-half-up bf16 (2 VALU ops); used for P in [0, ~20] — symmetric +/-2^-9 rel err
static __device__ inline unsigned short f2bf_r(float x) {
    union { float f; unsigned u; } v; v.f = x;
    return (unsigned short)((v.u + 0x8000u) >> 16);
}

static __device__ inline float bf2f(unsigned short u) {
    union { unsigned u; float f; } v; v.u = ((unsigned)u) << 16;
    return v.f;
}

static __device__ inline bf16x8 ldfrag(const unsigned short* p) {
    return __builtin_bit_cast(bf16x8, *(const u16x8*)p);
}

// K=16 bf16 MFMA: device pass has the _1k builtin (verified: round-4 device compile
// was clean); host pass has NO amdgcn builtins, so give it a parse-only fallback —
// host never executes kernel bodies.
#if __has_builtin(__builtin_amdgcn_mfma_f32_16x16x16bf16_1k)
#define MFMA16(a, b, c) __builtin_amdgcn_mfma_f32_16x16x16bf16_1k((a), (b), (c), 0, 0, 0)
#else
#define MFMA16(a, b, c) (c)
#endif

// ---------------- fused conversions: hidden->bf16, W->packed bf16, demb->transposed bf16 ----------------
// demb is pre-scaled by log2(e) so attn can use v_exp_f32 (base-2) with no per-element mul.
__global__ void conv_all(const float* __restrict__ x,
                         const float* __restrict__ Wq, const float* __restrict__ Wk,
                         const float* __restrict__ Wv, const float* __restrict__ demb,
                         unsigned short* __restrict__ xb, unsigned short* __restrict__ wall,
                         unsigned short* __restrict__ dembT) {
    int bid = blockIdx.x, tid = threadIdx.x;
    if (bid < 4096) {
        int i = bid * 256 + tid;                 // float4 index, 1M total
        float4 v = ((const float4*)x)[i];
        ushort4 o;
        o.x = f2bf(v.x); o.y = f2bf(v.y); o.z = f2bf(v.z); o.w = f2bf(v.w);
        ((ushort4*)xb)[i] = o;
    } else if (bid < 7168) {
        int i = (bid - 4096) * 256 + tid;        // float4 index, 768K total
        int e = i * 4;
        int which = e >> 20;                      // H*H = 1<<20 per matrix
        int r4 = (e & ((1 << 20) - 1)) >> 2;
        const float* src = which == 0 ? Wq : which == 1 ? Wk : Wv;
        float4 v = ((const float4*)src)[r4];
        ushort4 o;
        o.x = f2bf(v.x); o.y = f2bf(v.y); o.z = f2bf(v.z); o.w = f2bf(v.w);
        ((ushort4*)wall)[i] = o;
    } else {
        int t = (bid - 7168) * 256 + tid;        // 65536 total
        int h = t >> 12, e = t & 4095;
        dembT[t] = f2bf(demb[e * 16 + h] * 1.4426950408889634f);
    }
}

// ---------------- QKV GEMM (m97-style): [4096,1024] x [3072,1024]^T -> q/k/v bf16 [b,h,s,d] ----------------
__global__ __launch_bounds__(256) void gemm_qkv(
    const unsigned short* __restrict__ Xb, const unsigned short* __restrict__ Wall,
    const float* __restrict__ bq, const float* __restrict__ bk, const float* __restrict__ bv,
    unsigned short* __restrict__ Q, unsigned short* __restrict__ K, unsigned short* __restrict__ V)
{
    __shared__ unsigned short As[128 * 32];
    __shared__ unsigned short Bs[128 * 32];
    const int tid = threadIdx.x, lane = tid & 63, wv = tid >> 6;
    const int g = lane >> 4, l16 = lane & 15;
    const int wm = wv >> 1, wn = wv & 1;
    const int bm = blockIdx.y, bn = blockIdx.x;

    // one wave-instruction = 64 lanes x 16B = 1KB = 16 rows x 32 cols
    const int lrow = lane >> 2, lcol = (lane & 3) * 8;

    f32x4 acc[4][4];
    #pragma unroll
    for (int i = 0; i < 4; ++i)
        #pragma unroll
        for (int j = 0; j < 4; ++j) acc[i][j] = (f32x4){0.f, 0.f, 0.f, 0.f};

    for (int kt = 0; kt < 32; ++kt) {
        #pragma unroll
        for (int i = 0; i < 2; ++i) {
            int chunk = wv * 2 + i;                  // 0..7, each = 16 rows (128 rows total)
            int row = chunk * 16 + lrow;
            const unsigned short* ga = &Xb[(size_t)(bm * 128 + row) * 1024 + kt * 32 + lcol];
            const unsigned short* gb = &Wall[(size_t)(bn * 128 + row) * 1024 + kt * 32 + lcol];
            __builtin_amdgcn_global_load_lds((gu32_t*)(const void*)ga, (su32_t*)(void*)&As[chunk * 512], 16, 0, 0);
            __builtin_amdgcn_global_load_lds((gu32_t*)(const void*)gb, (su32_t*)(void*)&Bs[chunk * 512], 16, 0, 0);
        }
        __syncthreads();
        bf16x8 a[4], b[4];
        #pragma unroll
        for (int mi = 0; mi < 4; ++mi) a[mi] = ldfrag(&As[(wm * 64 + mi * 16 + l16) * 32 + g * 8]);
        #pragma unroll
        for (int ni = 0; ni < 4; ++ni) b[ni] = ldfrag(&Bs[(wn * 64 + ni * 16 + l16) * 32 + g * 8]);
        #pragma unroll
        for (int mi = 0; mi < 4; ++mi)
            #pragma unroll
            for (int ni = 0; ni < 4; ++ni)
                acc[mi][ni] = __builtin_amdgcn_mfma_f32_16x16x32_bf16(a[mi], b[ni], acc[mi][ni], 0, 0, 0);
        __syncthreads();
    }

    // epilogue: D row = g*4+r, col = l16
    #pragma unroll
    for (int mi = 0; mi < 4; ++mi) {
        #pragma unroll
        for (int ni = 0; ni < 4; ++ni) {
            int gn = bn * 128 + wn * 64 + ni * 16 + l16;
            int which = gn >> 10, nn = gn & 1023;
            int h = nn >> 6, d = nn & 63;
            float bias = which == 0 ? bq[nn] : which == 1 ? bk[nn] : bv[nn];
            unsigned short* dst = which == 0 ? Q : which == 1 ? K : V;
            #pragma unroll
            for (int r = 0; r < 4; ++r) {
                int gm = bm * 128 + wm * 64 + mi * 16 + g * 4 + r;
                int bb = gm >> 11, s = gm & 2047;
                dst[((size_t)(bb * 16 + h) * 2048 + s) * 64 + d] = f2bf(acc[mi][ni][r] + bias);
            }
        }
    }
}

// ---------------- V transpose: [b,h,s,d] -> [b,h,d,s] ----------------
__global__ void transpose_v(const unsigned short* __restrict__ V, unsigned short* __restrict__ VT) {
    __shared__ unsigned short t[64][65];
    int bh = blockIdx.y, st = blockIdx.x, tid = threadIdx.x;
    size_t ib = (size_t)bh * S_ * DH_ + (size_t)st * 64 * 64;   // contiguous 64x64 tile
    #pragma unroll
    for (int rep = 0; rep < 16; ++rep) {
        int e = rep * 256 + tid;
        t[e >> 6][e & 63] = V[ib + e];
    }
    __syncthreads();
    size_t ob = (size_t)bh * DH_ * S_ + st * 64;
    #pragma unroll
    for (int rep = 0; rep < 16; ++rep) {
        int e = rep * 256 + tid;
        int d = e >> 6, sl = e & 63;
        VT[ob + (size_t)d * S_ + sl] = t[sl][d];
    }
}

// ---------------- fused flash attention with relative bias ----------------
// LDS-unit-bound kernel (both prior structures pinned at ~100.6us with ~90% LDS busy).
// This version ELIMINATES the P LDS round-trip: QK^T is computed SWAPPED
// (mfma(A=K-slice, B=Q)) so C comes out col=l16=q, row=g*4+r=key -- which is exactly
// the A-fragment layout of mfma_f32_16x16x16_bf16 (k = g*4+j). exp'd P packs in-lane
// to short4 A-frags; PV runs as 16x K=16 MFMAs per wave against its exclusive 16-key
// slice (partial O sums). V B-frags are 4x ds_read_b64 (was 8x b128). Epilogue:
// cross-wave O reduction through LDS (2 phases, 24KB each) + tiny denominator table.
// Fixed-max softmax, base-2 exp (demb pre-scaled by log2e). LDS 24KB.
__global__ __launch_bounds__(256, 3) void attn(
    const unsigned short* __restrict__ Q, const unsigned short* __restrict__ K,
    const unsigned short* __restrict__ VT, const int* __restrict__ didx,
    const unsigned short* __restrict__ dembT, const float* __restrict__ mask,
    float* __restrict__ out)
{
    __shared__ __align__(16) unsigned char smem[24576];
    unsigned short* demb_h = (unsigned short*)smem;            // [4096] bf16 (main loop)
    unsigned short* Ks     = (unsigned short*)(smem + 8192);   // [64*64]
    unsigned short* Vs     = (unsigned short*)(smem + 16384);  // [64*64]
    float* tbl = (float*)smem;                                 // epilogue: [4 srcw][4 qtile][16]
    float* red = (float*)smem;                                 // epilogue: [6][4 dt][16 n][16 m] f32

    const int tid = threadIdx.x, lane = tid & 63, w = tid >> 6;
    const int g = lane >> 4, l16 = lane & 15;
    const int h = blockIdx.x, qt = blockIdx.y, b = blockIdx.z;
    const int bh = b * NH_ + h;

    // stage this head's demb column (bf16, contiguous, pre-scaled by log2e)
    #pragma unroll
    for (int j = 0; j < 2; ++j) {
        int i = j * 256 + tid;
        *(uint4*)&demb_h[i * 8] = *(const uint4*)&dembT[h * 4096 + i * 8];
    }

    // ALL 64 q-rows in registers as B-fragments (lane l16 = q, g*8 = dh chunk)
    bf16x8 qf[4][2];
    #pragma unroll
    for (int qtile = 0; qtile < 4; ++qtile) {
        size_t qbase = ((size_t)bh * S_ + qt * 64 + qtile * 16 + l16) * DH_;
        qf[qtile][0] = ldfrag(&Q[qbase + g * 8]);
        qf[qtile][1] = ldfrag(&Q[qbase + 32 + g * 8]);
    }

    f32x4 oa[4][4];            // [qtile][dt]: partial O^(this wave's k-slice); row=q-off g*4+r, col=d-off l16
    float lsum[4];             // per-lane partial denominators (q = qtile*16+l16, k in slice)
    #pragma unroll
    for (int i = 0; i < 4; ++i) {
        lsum[i] = 0.f;
        #pragma unroll
        for (int j = 0; j < 4; ++j) oa[i][j] = (f32x4){0.f, 0.f, 0.f, 0.f};
    }

    const size_t kbase = (size_t)bh * S_ * DH_;
    const size_t vbase = (size_t)bh * DH_ * S_;
    const int kg0 = w * 16 + g * 4;        // lane's key-offset base within a 64-key tile

    __syncthreads();   // demb_h ready

    for (int kt = 0; kt < 32; ++kt) {
        // ---- stage K/V tile: global -> LDS (xor-swizzled 8-elem chunks) ----
        #pragma unroll
        for (int j = 0; j < 2; ++j) {
            int e = j * 2048 + tid * 8;
            int r = e >> 6, c = e & 63;
            int sidx = r * 64 + ((((c >> 3) ^ (r & 7))) << 3);
            *(uint4*)&Ks[sidx] = *(const uint4*)&K[kbase + (size_t)kt * 4096 + e];
            *(uint4*)&Vs[sidx] = *(const uint4*)&VT[vbase + (size_t)r * S_ + kt * 64 + c];
        }

        // ---- didx (vectorized int4: k-consecutive) + mask (float4) for THIS iter ----
        const int kg = kt * 64 + kg0;
        int4 di0 = *(const int4*)&didx[(qt * 64 + 0 * 16 + l16) * S_ + kg];
        int4 di1 = *(const int4*)&didx[(qt * 64 + 1 * 16 + l16) * S_ + kg];
        int4 di2 = *(const int4*)&didx[(qt * 64 + 2 * 16 + l16) * S_ + kg];
        int4 di3 = *(const int4*)&didx[(qt * 64 + 3 * 16 + l16) * S_ + kg];
        float4 mv = *(const float4*)&mask[b * S_ + kg];
        __syncthreads();   // barrier 1: K/V visible

        // K-slice A-fragments (16 keys owned by this wave, read once)
        const int krow = w * 16 + l16, km = krow & 7;
        bf16x8 kf0 = ldfrag(&Ks[krow * 64 + ((g ^ km) << 3)]);
        bf16x8 kf1 = ldfrag(&Ks[krow * 64 + (((g + 4) ^ km) << 3)]);

        // V B-fragments for K=16 PV: lane l16 = d-row, k = w*16 + g*4..+3 (ds_read_b64)
        i16x4 vf[4];
        #pragma unroll
        for (int dt = 0; dt < 4; ++dt) {
            int vrow = dt * 16 + l16, vm = vrow & 7;
            int chunkc = w * 2 + (g >> 1);
            int addr = vrow * 64 + (((chunkc ^ vm)) << 3) + ((g & 1) << 2);
            vf[dt] = *(const i16x4*)&Vs[addr];
        }

        // ---- QK^T swapped: C[m=key(g*4+r)][n=q(l16)] ----
        f32x4 z0, z1, z2, z3;
        __builtin_amdgcn_s_setprio(1);
        {
            f32x4 zz = (f32x4){0.f, 0.f, 0.f, 0.f};
            zz = __builtin_amdgcn_mfma_f32_16x16x32_bf16(kf0, qf[0][0], zz, 0, 0, 0);
            z0 = __builtin_amdgcn_mfma_f32_16x16x32_bf16(kf1, qf[0][1], zz, 0, 0, 0);
            zz = (f32x4){0.f, 0.f, 0.f, 0.f};
            zz = __builtin_amdgcn_mfma_f32_16x16x32_bf16(kf0, qf[1][0], zz, 0, 0, 0);
            z1 = __builtin_amdgcn_mfma_f32_16x16x32_bf16(kf1, qf[1][1], zz, 0, 0, 0);
            zz = (f32x4){0.f, 0.f, 0.f, 0.f};
            zz = __builtin_amdgcn_mfma_f32_16x16x32_bf16(kf0, qf[2][0], zz, 0, 0, 0);
            z2 = __builtin_amdgcn_mfma_f32_16x16x32_bf16(kf1, qf[2][1], zz, 0, 0, 0);
            zz = (f32x4){0.f, 0.f, 0.f, 0.f};
            zz = __builtin_amdgcn_mfma_f32_16x16x32_bf16(kf0, qf[3][0], zz, 0, 0, 0);
            z3 = __builtin_amdgcn_mfma_f32_16x16x32_bf16(kf1, qf[3][1], zz, 0, 0, 0);
        }
        __builtin_amdgcn_s_setprio(0);

        // ---- exp (base-2) + in-lane pack to PV A-fragments (no LDS round-trip) ----
        const float ml0 = mv.x * 1.4426950408889634f;
        const float ml1 = mv.y * 1.4426950408889634f;
        const float ml2 = mv.z * 1.4426950408889634f;
        const float ml3 = mv.w * 1.4426950408889634f;
        i16x4 pa0, pa1, pa2, pa3;
        #define EXPPACK(ZZ, DI, PA, QIDX)                                                   \
        {                                                                                   \
            float p0 = __builtin_amdgcn_exp2f(fmaf(ZZ[0], 0.18033688011112042f,             \
                        bf2f(demb_h[DI.x]) + ml0));                                         \
            float p1 = __builtin_amdgcn_exp2f(fmaf(ZZ[1], 0.18033688011112042f,             \
                        bf2f(demb_h[DI.y]) + ml1));                                         \
            float p2 = __builtin_amdgcn_exp2f(fmaf(ZZ[2], 0.18033688011112042f,             \
                        bf2f(demb_h[DI.z]) + ml2));                                         \
            float p3 = __builtin_amdgcn_exp2f(fmaf(ZZ[3], 0.18033688011112042f,             \
                        bf2f(demb_h[DI.w]) + ml3));                                         \
            lsum[QIDX] += (p0 + p1) + (p2 + p3);                                            \
            PA[0] = (short)f2bf_r(p0); PA[1] = (short)f2bf_r(p1);                           \
            PA[2] = (short)f2bf_r(p2); PA[3] = (short)f2bf_r(p3);                           \
        }
        EXPPACK(z0, di0, pa0, 0)
        EXPPACK(z1, di1, pa1, 1)
        EXPPACK(z2, di2, pa2, 2)
        EXPPACK(z3, di3, pa3, 3)
        #undef EXPPACK

        // ---- PV partial (K=16): oa[qtile][dt] += P_slice x V_slice ----
        __builtin_amdgcn_s_setprio(1);
        #pragma unroll
        for (int dt = 0; dt < 4; ++dt) {
            oa[0][dt] = MFMA16(pa0, vf[dt], oa[0][dt]);
            oa[1][dt] = MFMA16(pa1, vf[dt], oa[1][dt]);
            oa[2][dt] = MFMA16(pa2, vf[dt], oa[2][dt]);
            oa[3][dt] = MFMA16(pa3, vf[dt], oa[3][dt]);
        }
        __builtin_amdgcn_s_setprio(0);
        __syncthreads();   // barrier 2: Ks/Vs free for next tile
    }

    // ================= epilogue =================
    // 1) denominators: reduce lsum over g (shfl), then across waves via tiny LDS table
    #pragma unroll
    for (int t = 0; t < 4; ++t) {
        lsum[t] += __shfl_xor(lsum[t], 16);
        lsum[t] += __shfl_xor(lsum[t], 32);
    }
    if (lane < 16) {
        #pragma unroll
        for (int t = 0; t < 4; ++t) tbl[(w * 4 + t) * 16 + l16] = lsum[t];
    }
    __syncthreads();
    f32x4 dsum = (f32x4){0.f, 0.f, 0.f, 0.f};
    #pragma unroll
    for (int sw = 0; sw < 4; ++sw) dsum += *(const f32x4*)&tbl[(sw * 4 + w) * 16 + g * 4];
    f32x4 linv;
    #pragma unroll
    for (int r = 0; r < 4; ++r) linv[r] = __builtin_amdgcn_rcpf(dsum[r]);
    __syncthreads();   // tbl consumed; red may overwrite pool

    // 2) cross-wave O reduction: wave t becomes owner of qtile t. Two 24KB phases.
    // phase A: targets 0,1
    #pragma unroll
    for (int t = 0; t < 2; ++t) {
        if (w != t) {
            int slot = w < t ? w : w - 1;
            #pragma unroll
            for (int dt = 0; dt < 4; ++dt)
                *(f32x4*)&red[(((t * 3 + slot) * 4 + dt) * 16 + l16) * 16 + g * 4] = oa[t][dt];
        }
    }
    __syncthreads();
    if (w == 0) {
        #pragma unroll
        for (int slot = 0; slot < 3; ++slot)
            #pragma unroll
            for (int dt = 0; dt < 4; ++dt)
                oa[0][dt] += *(const f32x4*)&red[(((0 * 3 + slot) * 4 + dt) * 16 + l16) * 16 + g * 4];
    } else if (w == 1) {
        #pragma unroll
        for (int slot = 0; slot < 3; ++slot)
            #pragma unroll
            for (int dt = 0; dt < 4; ++dt)
                oa[1][dt] += *(const f32x4*)&red[(((1 * 3 + slot) * 4 + dt) * 16 + l16) * 16 + g * 4];
    }
    __syncthreads();
    // phase B: targets 2,3
    #pragma unroll
    for (int t2 = 0; t2 < 2; ++t2) {
        const int t = 2 + t2;
        if (w != t) {
            int slot = w < t ? w : w - 1;
            #pragma unroll
            for (int dt = 0; dt < 4; ++dt)
                *(f32x4*)&red[(((t2 * 3 + slot) * 4 + dt) * 16 + l16) * 16 + g * 4] = oa[t][dt];
        }
    }
    __syncthreads();
    if (w == 2) {
        #pragma unroll
        for (int slot = 0; slot < 3; ++slot)
            #pragma unroll
            for (int dt = 0; dt < 4; ++dt)
                oa[2][dt] += *(const f32x4*)&red[(((0 * 3 + slot) * 4 + dt) * 16 + l16) * 16 + g * 4];
    } else if (w == 3) {
        #pragma unroll
        for (int slot = 0; slot < 3; ++slot)
            #pragma unroll
            for (int dt = 0; dt < 4; ++dt)
                oa[3][dt] += *(const f32x4*)&red[(((1 * 3 + slot) * 4 + dt) * 16 + l16) * 16 + g * 4];
    }

    // 3) normalize + store (wave w owns qtile w; rows q=g*4+r, cols d=dt*16+l16 -> coalesced)
    #define STORE_QT(T)                                                                     \
    if (w == T) {                                                                           \
        _Pragma("unroll")                                                                   \
        for (int dt = 0; dt < 4; ++dt) {                                                    \
            _Pragma("unroll")                                                               \
            for (int r = 0; r < 4; ++r) {                                                   \
                int s = qt * 64 + T * 16 + g * 4 + r;                                       \
                out[((size_t)b * S_ + s) * H_ + h * DH_ + dt * 16 + l16] =                  \
                    oa[T][dt][r] * linv[r];                                                 \
            }                                                                               \
        }                                                                                   \
    }
    STORE_QT(0) else STORE_QT(1) else STORE_QT(2) else STORE_QT(3)
    #undef STORE_QT
}

extern "C" void kernel_launch(void* const* d_in, const int* in_sizes, int n_in,
                              void* d_out, int out_size, void* d_ws, size_t ws_size,
                              hipStream_t stream) {
    const float* hidden = (const float*)d_in[0];
    const float* mask   = (const float*)d_in[1];
    const int*   didx   = (const int*)d_in[2];
    const float* Wq     = (const float*)d_in[3];
    const float* bq     = (const float*)d_in[4];
    const float* Wk     = (const float*)d_in[5];
    const float* bk     = (const float*)d_in[6];
    const float* Wv     = (const float*)d_in[7];
    const float* bv     = (const float*)d_in[8];
    const float* demb   = (const float*)d_in[9];
    float* out = (float*)d_out;

    unsigned short* ws = (unsigned short*)d_ws;
    unsigned short* Xb   = ws;                        // 4096*1024
    unsigned short* Wall = Xb + 4096 * 1024;          // 3072*1024
    unsigned short* Qb   = Wall + 3072 * 1024;        // 4194304 each
    unsigned short* Kb   = Qb + 4194304;
    unsigned short* Vb   = Kb + 4194304;
    unsigned short* VTb  = Vb + 4194304;
    unsigned short* DembT = VTb + 4194304;            // 65536 (bf16 [16][4096])

    conv_all<<<7424, 256, 0, stream>>>(hidden, Wq, Wk, Wv, demb, Xb, Wall, DembT);
    gemm_qkv<<<dim3(24, 32), 256, 0, stream>>>(Xb, Wall, bq, bk, bv, Qb, Kb, Vb);
    transpose_v<<<dim3(32, 32), 256, 0, stream>>>(Vb, VTb);
    attn<<<dim3(16, 32, 2), 256, 0, stream>>>(Qb, Kb, VTb, didx, DembT, mask, out);
}

// Round 6
// 226.441 us; speedup vs baseline: 1.0635x; 1.0635x over previous
//
#include <hip/hip_runtime.h>
#include <hip/hip_bf16.h>

#define B_   2
#define S_   2048
#define H_   1024
#define NH_  16
#define DH_  64

typedef __attribute__((ext_vector_type(8))) __bf16 bf16x8;
typedef __attribute__((ext_vector_type(8))) unsigned short u16x8;
typedef __attribute__((ext_vector_type(4))) float f32x4;

typedef const __attribute__((address_space(1))) unsigned int gu32_t;
typedef __attribute__((address_space(3))) unsigned int su32_t;

static __device__ inline unsigned short f2bf(float x) {
    union { float f; unsigned u; } v; v.f = x;
    unsigned r = v.u + 0x7fffu + ((v.u >> 16) & 1u);
    return (unsigned short)(r >> 16);
}

// fast round-half-up bf16 (2 VALU ops); used for P in [0, ~20] — symmetric +/-2^-9 rel err
static __device__ inline unsigned short f2bf_r(float x) {
    union { float f; unsigned u; } v; v.f = x;
    return (unsigned short)((v.u + 0x8000u) >> 16);
}

static __device__ inline float bf2f(unsigned short u) {
    union { unsigned u; float f; } v; v.u = ((unsigned)u) << 16;
    return v.f;
}

static __device__ inline bf16x8 ldfrag(const unsigned short* p) {
    return __builtin_bit_cast(bf16x8, *(const u16x8*)p);
}

// ---------------- fused conversions: hidden->bf16, W->packed bf16, demb->transposed bf16 ----------------
__global__ void conv_all(const float* __restrict__ x,
                         const float* __restrict__ Wq, const float* __restrict__ Wk,
                         const float* __restrict__ Wv, const float* __restrict__ demb,
                         unsigned short* __restrict__ xb, unsigned short* __restrict__ wall,
                         unsigned short* __restrict__ dembT) {
    int bid = blockIdx.x, tid = threadIdx.x;
    if (bid < 4096) {
        int i = bid * 256 + tid;                 // float4 index, 1M total
        float4 v = ((const float4*)x)[i];
        ushort4 o;
        o.x = f2bf(v.x); o.y = f2bf(v.y); o.z = f2bf(v.z); o.w = f2bf(v.w);
        ((ushort4*)xb)[i] = o;
    } else if (bid < 7168) {
        int i = (bid - 4096) * 256 + tid;        // float4 index, 768K total
        int e = i * 4;
        int which = e >> 20;                      // H*H = 1<<20 per matrix
        int r4 = (e & ((1 << 20) - 1)) >> 2;
        const float* src = which == 0 ? Wq : which == 1 ? Wk : Wv;
        float4 v = ((const float4*)src)[r4];
        ushort4 o;
        o.x = f2bf(v.x); o.y = f2bf(v.y); o.z = f2bf(v.z); o.w = f2bf(v.w);
        ((ushort4*)wall)[i] = o;
    } else {
        int t = (bid - 7168) * 256 + tid;        // 65536 total
        int h = t >> 12, e = t & 4095;
        dembT[t] = f2bf(demb[e * 16 + h]);
    }
}

// ---------------- QKV GEMM: [4096,1024] x [3072,1024]^T -> q/k/v bf16 [b,h,s,d] ----------------
// T3-minimum/T14: double-buffered LDS; next K-tile's global_load_lds issued BEFORE the
// current tile's ds_read+MFMA, so HBM latency hides under compute. ONE barrier per iter
// (its implicit vmcnt(0)+lgkmcnt(0) drain is exactly the wait the staged loads need).
// Was: stage -> barrier(immediate vmcnt drain = full latency exposed) -> compute -> barrier.
__global__ __launch_bounds__(256) void gemm_qkv(
    const unsigned short* __restrict__ Xb, const unsigned short* __restrict__ Wall,
    const float* __restrict__ bq, const float* __restrict__ bk, const float* __restrict__ bv,
    unsigned short* __restrict__ Q, unsigned short* __restrict__ K, unsigned short* __restrict__ V)
{
    __shared__ unsigned short As[2][128 * 32];
    __shared__ unsigned short Bs[2][128 * 32];
    const int tid = threadIdx.x, lane = tid & 63, wv = tid >> 6;
    const int g = lane >> 4, l16 = lane & 15;
    const int wm = wv >> 1, wn = wv & 1;
    const int bm = blockIdx.y, bn = blockIdx.x;

    // one wave-instruction = 64 lanes x 16B = 1KB = 16 rows x 32 cols
    const int lrow = lane >> 2, lcol = (lane & 3) * 8;

    f32x4 acc[4][4];
    #pragma unroll
    for (int i = 0; i < 4; ++i)
        #pragma unroll
        for (int j = 0; j < 4; ++j) acc[i][j] = (f32x4){0.f, 0.f, 0.f, 0.f};

    // per-thread invariant staging geometry
    const int chunk0 = wv * 2, chunk1 = wv * 2 + 1;          // each chunk = 16 rows
    const size_t arow0 = (size_t)(bm * 128 + chunk0 * 16 + lrow) * 1024 + lcol;
    const size_t arow1 = (size_t)(bm * 128 + chunk1 * 16 + lrow) * 1024 + lcol;
    const size_t brow0 = (size_t)(bn * 128 + chunk0 * 16 + lrow) * 1024 + lcol;
    const size_t brow1 = (size_t)(bn * 128 + chunk1 * 16 + lrow) * 1024 + lcol;

#define STAGE(BUF, KT)                                                                      \
    {                                                                                       \
        __builtin_amdgcn_global_load_lds((gu32_t*)(const void*)&Xb[arow0 + (KT) * 32],      \
            (su32_t*)(void*)&As[BUF][chunk0 * 512], 16, 0, 0);                              \
        __builtin_amdgcn_global_load_lds((gu32_t*)(const void*)&Wall[brow0 + (KT) * 32],    \
            (su32_t*)(void*)&Bs[BUF][chunk0 * 512], 16, 0, 0);                              \
        __builtin_amdgcn_global_load_lds((gu32_t*)(const void*)&Xb[arow1 + (KT) * 32],      \
            (su32_t*)(void*)&As[BUF][chunk1 * 512], 16, 0, 0);                              \
        __builtin_amdgcn_global_load_lds((gu32_t*)(const void*)&Wall[brow1 + (KT) * 32],    \
            (su32_t*)(void*)&Bs[BUF][chunk1 * 512], 16, 0, 0);                              \
    }

    // prologue: tile 0 into buffer 0
    STAGE(0, 0)
    __syncthreads();                       // drains vmcnt(0): buffer 0 ready

    int cur = 0;
    for (int kt = 0; kt < 32; ++kt) {
        // issue next tile's loads first (latency hides under this tile's compute)
        if (kt < 31) STAGE(cur ^ 1, kt + 1)

        bf16x8 a[4], b[4];
        #pragma unroll
        for (int mi = 0; mi < 4; ++mi) a[mi] = ldfrag(&As[cur][(wm * 64 + mi * 16 + l16) * 32 + g * 8]);
        #pragma unroll
        for (int ni = 0; ni < 4; ++ni) b[ni] = ldfrag(&Bs[cur][(wn * 64 + ni * 16 + l16) * 32 + g * 8]);
        #pragma unroll
        for (int mi = 0; mi < 4; ++mi)
            #pragma unroll
            for (int ni = 0; ni < 4; ++ni)
                acc[mi][ni] = __builtin_amdgcn_mfma_f32_16x16x32_bf16(a[mi], b[ni], acc[mi][ni], 0, 0, 0);

        __syncthreads();                   // drains vmcnt(0): next buffer staged; cur reads done
        cur ^= 1;
    }
#undef STAGE

    // epilogue: D row = g*4+r, col = l16
    #pragma unroll
    for (int mi = 0; mi < 4; ++mi) {
        #pragma unroll
        for (int ni = 0; ni < 4; ++ni) {
            int gn = bn * 128 + wn * 64 + ni * 16 + l16;
            int which = gn >> 10, nn = gn & 1023;
            int h = nn >> 6, d = nn & 63;
            float bias = which == 0 ? bq[nn] : which == 1 ? bk[nn] : bv[nn];
            unsigned short* dst = which == 0 ? Q : which == 1 ? K : V;
            #pragma unroll
            for (int r = 0; r < 4; ++r) {
                int gm = bm * 128 + wm * 64 + mi * 16 + g * 4 + r;
                int bb = gm >> 11, s = gm & 2047;
                dst[((size_t)(bb * 16 + h) * 2048 + s) * 64 + d] = f2bf(acc[mi][ni][r] + bias);
            }
        }
    }
}

// ---------------- V transpose: [b,h,s,d] -> [b,h,d,s] ----------------
__global__ void transpose_v(const unsigned short* __restrict__ V, unsigned short* __restrict__ VT) {
    __shared__ unsigned short t[64][65];
    int bh = blockIdx.y, st = blockIdx.x, tid = threadIdx.x;
    size_t ib = (size_t)bh * S_ * DH_ + (size_t)st * 64 * 64;   // contiguous 64x64 tile
    #pragma unroll
    for (int rep = 0; rep < 16; ++rep) {
        int e = rep * 256 + tid;
        t[e >> 6][e & 63] = V[ib + e];
    }
    __syncthreads();
    size_t ob = (size_t)bh * DH_ * S_ + st * 64;
    #pragma unroll
    for (int rep = 0; rep < 16; ++rep) {
        int e = rep * 256 + tid;
        int d = e >> 6, sl = e & 63;
        VT[ob + (size_t)d * S_ + sl] = t[sl][d];
    }
}

// ---------------- fused flash attention with relative bias ----------------
// ROUND-0 VERBATIM (best verified: 100.6us). Fixed-max softmax (scores bounded ~|3|;
// exp(-inf)=0 still handles -inf masks): no per-iter max/rescale, l accumulated
// per-lane, reduced once at end. LDS: demb_h 8KB + Ks 8KB + Vs 8KB + Ps 8KB = 32KB.
__global__ __launch_bounds__(256, 4) void attn(
    const unsigned short* __restrict__ Q, const unsigned short* __restrict__ K,
    const unsigned short* __restrict__ VT, const int* __restrict__ didx,
    const unsigned short* __restrict__ dembT, const float* __restrict__ mask,
    float* __restrict__ out)
{
    __shared__ unsigned short demb_h[4096];
    __shared__ unsigned short Ks[64 * 64];
    __shared__ unsigned short Vs[64 * 64];
    __shared__ unsigned short Ps[4][16 * 64];
    const int tid = threadIdx.x, lane = tid & 63, w = tid >> 6;
    const int g = lane >> 4, l16 = lane & 15;
    const int h = blockIdx.x, qt = blockIdx.y, b = blockIdx.z;
    const int bh = b * NH_ + h;
    const int qr = qt * 64 + w * 16;

    // stage this head's demb column (bf16, contiguous)
    #pragma unroll
    for (int j = 0; j < 2; ++j) {
        int i = j * 256 + tid;
        *(uint4*)&demb_h[i * 8] = *(const uint4*)&dembT[h * 4096 + i * 8];
    }

    bf16x8 qf[2];
    {
        size_t qbase = ((size_t)bh * S_ + qr + l16) * DH_;
        qf[0] = ldfrag(&Q[qbase + g * 8]);
        qf[1] = ldfrag(&Q[qbase + 32 + g * 8]);
    }

    f32x4 oa[4];
    float lsum[4];
    #pragma unroll
    for (int i = 0; i < 4; ++i) {
        oa[i] = (f32x4){0.f, 0.f, 0.f, 0.f};
        lsum[i] = 0.f;
    }

    const size_t kbase = (size_t)bh * S_ * DH_;
    const size_t vbase = (size_t)bh * DH_ * S_;

    __syncthreads();

    for (int kt = 0; kt < 32; ++kt) {
        #pragma unroll
        for (int j = 0; j < 2; ++j) {
            int e = j * 2048 + tid * 8;
            int r = e >> 6, c = e & 63;
            int sidx = r * 64 + ((((c >> 3) ^ (r & 7))) << 3);
            *(uint4*)&Ks[sidx] = *(const uint4*)&K[kbase + (size_t)kt * 64 * 64 + e];
            *(uint4*)&Vs[sidx] = *(const uint4*)&VT[vbase + (size_t)r * S_ + kt * 64 + c];
        }

        // issue didx + mask loads early (hide L2/L3 latency behind staging)
        int ei[4][4];
        float mk[4];
        #pragma unroll
        for (int kj = 0; kj < 4; ++kj) {
            int kg = kt * 64 + kj * 16 + l16;
            mk[kj] = mask[b * S_ + kg];
            #pragma unroll
            for (int r = 0; r < 4; ++r) {
                int qg = qr + g * 4 + r;
                ei[kj][r] = didx[qg * S_ + kg];
            }
        }

        __syncthreads();

        // QK^T: 4 column tiles of 16 keys
        f32x4 sc[4];
        #pragma unroll
        for (int kj = 0; kj < 4; ++kj) {
            int row = kj * 16 + l16, m = row & 7;
            bf16x8 kf0 = ldfrag(&Ks[row * 64 + ((g ^ m) << 3)]);
            bf16x8 kf1 = ldfrag(&Ks[row * 64 + (((g + 4) ^ m) << 3)]);
            f32x4 z = (f32x4){0.f, 0.f, 0.f, 0.f};
            z = __builtin_amdgcn_mfma_f32_16x16x32_bf16(qf[0], kf0, z, 0, 0, 0);
            z = __builtin_amdgcn_mfma_f32_16x16x32_bf16(qf[1], kf1, z, 0, 0, 0);
            sc[kj] = z;
        }

        // p = exp(score*0.125 + bias + mask); accumulate per-lane row sums
        #pragma unroll
        for (int kj = 0; kj < 4; ++kj) {
            #pragma unroll
            for (int r = 0; r < 4; ++r) {
                float bm = bf2f(demb_h[ei[kj][r]]) + mk[kj];
                float p = __expf(fmaf(sc[kj][r], 0.125f, bm));
                lsum[r] += p;
                int row = g * 4 + r;
                int idx = row * 64 + ((((kj * 2 + (l16 >> 3)) ^ (row & 7))) << 3) + (l16 & 7);
                Ps[w][idx] = f2bf_r(p);
            }
        }

        // PV: P (A-layout from LDS) x V — no rescale needed (fixed max)
        int pm = l16 & 7;
        bf16x8 pf0 = ldfrag(&Ps[w][l16 * 64 + ((g ^ pm) << 3)]);
        bf16x8 pf1 = ldfrag(&Ps[w][l16 * 64 + (((g + 4) ^ pm) << 3)]);
        #pragma unroll
        for (int dt = 0; dt < 4; ++dt) {
            int row = dt * 16 + l16, m = row & 7;
            bf16x8 vf0 = ldfrag(&Vs[row * 64 + ((g ^ m) << 3)]);
            bf16x8 vf1 = ldfrag(&Vs[row * 64 + (((g + 4) ^ m) << 3)]);
            oa[dt] = __builtin_amdgcn_mfma_f32_16x16x32_bf16(pf0, vf0, oa[dt], 0, 0, 0);
            oa[dt] = __builtin_amdgcn_mfma_f32_16x16x32_bf16(pf1, vf1, oa[dt], 0, 0, 0);
        }
        __syncthreads();
    }

    // one final 16-lane reduction of the row sums
    float linv[4];
    #pragma unroll
    for (int r = 0; r < 4; ++r) {
        float s = lsum[r];
        s += __shfl_xor(s, 1);
        s += __shfl_xor(s, 2);
        s += __shfl_xor(s, 4);
        s += __shfl_xor(s, 8);
        linv[r] = __builtin_amdgcn_rcpf(s);
    }

    #pragma unroll
    for (int dt = 0; dt < 4; ++dt) {
        #pragma unroll
        for (int r = 0; r < 4; ++r) {
            int s = qr + g * 4 + r;
            int d = dt * 16 + l16;
            out[((size_t)b * S_ + s) * H_ + h * DH_ + d] = oa[dt][r] * linv[r];
        }
    }
}

extern "C" void kernel_launch(void* const* d_in, const int* in_sizes, int n_in,
                              void* d_out, int out_size, void* d_ws, size_t ws_size,
                              hipStream_t stream) {
    const float* hidden = (const float*)d_in[0];
    const float* mask   = (const float*)d_in[1];
    const int*   didx   = (const int*)d_in[2];
    const float* Wq     = (const float*)d_in[3];
    const float* bq     = (const float*)d_in[4];
    const float* Wk     = (const float*)d_in[5];
    const float* bk     = (const float*)d_in[6];
    const float* Wv     = (const float*)d_in[7];
    const float* bv     = (const float*)d_in[8];
    const float* demb   = (const float*)d_in[9];
    float* out = (float*)d_out;

    unsigned short* ws = (unsigned short*)d_ws;
    unsigned short* Xb   = ws;                        // 4096*1024
    unsigned short* Wall = Xb + 4096 * 1024;          // 3072*1024
    unsigned short* Qb   = Wall + 3072 * 1024;        // 4194304 each
    unsigned short* Kb   = Qb + 4194304;
    unsigned short* Vb   = Kb + 4194304;
    unsigned short* VTb  = Vb + 4194304;
    unsigned short* DembT = VTb + 4194304;            // 65536 (bf16 [16][4096])

    conv_all<<<7424, 256, 0, stream>>>(hidden, Wq, Wk, Wv, demb, Xb, Wall, DembT);
    gemm_qkv<<<dim3(24, 32), 256, 0, stream>>>(Xb, Wall, bq, bk, bv, Qb, Kb, Vb);
    transpose_v<<<dim3(32, 32), 256, 0, stream>>>(Vb, VTb);
    attn<<<dim3(16, 32, 2), 256, 0, stream>>>(Qb, Kb, VTb, didx, DembT, mask, out);
}